// Round 17
// baseline (367.596 us; speedup 1.0000x reference)
//
#include <hip/hip_runtime.h>
#include <hip/hip_bf16.h>
#include <stdint.h>

#define E_NUM 16
#define T_NUM 8192
#define H_DIM 1024
#define I_DIM 4096
#define MPE   512   // tokens per expert

typedef __attribute__((ext_vector_type(8))) short short8;
typedef __attribute__((ext_vector_type(4))) float f32x4;
using bf16 = __hip_bfloat16;

typedef const __attribute__((address_space(1))) void GLV;
typedef __attribute__((address_space(3))) void LDSV;

__device__ __forceinline__ uint32_t pack2_bf16(float a, float b) {
  union { float f; uint32_t u; } ua, ub;
  ua.f = a; ub.f = b;
  uint32_t x = ua.u + (0x7FFFu + ((ua.u >> 16) & 1u));
  uint32_t y = ub.u + (0x7FFFu + ((ub.u >> 16) & 1u));
  return (x >> 16) | (y & 0xFFFF0000u);
}

// 8 f32 (two float4) -> uint4 of 8 bf16 (RNE, v_cvt_pk_bf16_f32)
__device__ __forceinline__ uint4 cvt8u(float4 a, float4 b) {
  union { uint4 u; __hip_bfloat162 h[4]; } r;
  r.h[0] = __float22bfloat162_rn({a.x, a.y});
  r.h[1] = __float22bfloat162_rn({a.z, a.w});
  r.h[2] = __float22bfloat162_rn({b.x, b.y});
  r.h[3] = __float22bfloat162_rn({b.z, b.w});
  return r.u;
}

// fast GELU (validated R10/R12/R13/R15: absmax unchanged at 0.03125)
__device__ __forceinline__ float fast_gelu(float x) {
  const float p = x * fmaf(x * x, -0.0713548162726f, -1.59576912161f);
  return x * __builtin_amdgcn_rcpf(1.0f + __expf(p));
}

// ---------------- gather + cast: xp[r] = bf16(hs[perm[r]]) ----------------
__global__ __launch_bounds__(256)
void gather_cast_kernel(const float* __restrict__ hs, const int* __restrict__ perm,
                        uint32_t* __restrict__ xp) {
  const int r = blockIdx.x;
  const int t = threadIdx.x;
  const int src = perm[r];
  float4 v = ((const float4*)(hs + (size_t)src * H_DIM))[t];
  uint2 o;
  o.x = pack2_bf16(v.x, v.y);
  o.y = pack2_bf16(v.z, v.w);
  ((uint2*)(xp + (size_t)r * (H_DIM / 2)))[t] = o;
}

// ------ grouped GEMM: BM=256/BN=128/BK=64, glds-A + 2-ahead bf16-B ---------
// C = A(bf16,[E][512][K]) * B(f32,[E][N][K])^T.  512 thr = 8 waves (4M x 2N),
// per-wave 64x64 (4x4 frags), acc 64 VGPR.  Triple-buffered LDS 144 KB:
//   A: [256][64] bf16 x3 (glds-direct, chunk^(row&7) pre-swizzled source)
//   B: [128][64] bf16 x3 (f32->regs 2 iters ahead, cvt_pk, swizzled ds_write)
// Per iter t: issue {A-glds,B-loads}(t+2) -> vmcnt(8) retires ALL of (t+1)
// [t+2's 8 ops stay in flight] -> ds_write B(t+1) -> ds_read+MFMA(t) x2 ksteps
// -> lgkmcnt(0) -> s_barrier.  No full vmem drain in steady state.
// EPI=1: gelu -> bf16 Hout, LDS-coalesced stores.  EPI=0: +bias, f32 scatter.
template<int EPI, int N, int K, int LOG_NBN, int NWG>
__global__ __launch_bounds__(512, 1)
void moe_gemm_kernel(const bf16* __restrict__ A, const float* __restrict__ Bw,
                     const float* __restrict__ bias, bf16* __restrict__ Hout,
                     float* __restrict__ Oout, const int* __restrict__ perm) {
  constexpr int NK = K / 64;
  __shared__ bf16 As[3][256 * 64];   // 32 KB each
  __shared__ bf16 Bs[3][128 * 64];   // 16 KB each   (total 144 KB)

  // bijective chunked XCD swizzle (m204); NWG % 8 == 0; bm fastest
  constexpr int qx = NWG >> 3;
  const int orig = blockIdx.x;
  const int wg = (orig & 7) * qx + (orig >> 3);
  const int bm = wg & 1;
  const int bn = (wg >> 1) & ((1 << LOG_NBN) - 1);
  const int e  = wg >> (1 + LOG_NBN);

  const int tid = threadIdx.x;
  const int l = tid & 63;
  const int wv = tid >> 6;                 // 0..7
  const int wr = wv >> 1, wc = wv & 1;     // 4 M-waves x 2 N-waves
  const int fr = l & 15, fq = l >> 4;
  const int rx = fr & 7;

  const bf16*  Ae = A  + ((size_t)e * MPE + (size_t)bm * 256) * K;
  const float* Be = Bw + ((size_t)e * N + (size_t)bn * 128) * K;

  // A staging (R2/R9-validated geometry): granule j = i*512+tid (i=0..3);
  // row = j>>3 = i*64 + (tid>>3); slot s = tid&7; logical chunk c = s^(row&7).
  const int ar = tid >> 3;
  const bf16* Asrc = Ae + (size_t)ar * K + (((tid & 7) ^ (ar & 7)) << 3);

  // B staging (R4/R5-validated geometry): row br = tid>>2, seg bs = tid&3
  // (16 f32 each); swizzled bf16 write offsets (elements).
  const int br = tid >> 2, bs = tid & 3;
  const float* Bsrc = Be + (size_t)br * K + bs * 16;
  const int bwo0 = br * 64 + ((((bs << 1))     ^ (br & 7)) << 3);
  const int bwo1 = br * 64 + ((((bs << 1) | 1) ^ (br & 7)) << 3);

  // fragment read offsets (elements); chunk = (kk*4+fq)^rx
  const int aro = (wr * 64 + fr) * 64;     // + m*1024 + chunk*8
  const int bro = (wc * 64 + fr) * 64;     // + n*1024 + chunk*8
  const int ch0 = ((0 * 4 + fq) ^ rx) << 3;
  const int ch1 = ((1 * 4 + fq) ^ rx) << 3;

  f32x4 acc[4][4];
#pragma unroll
  for (int m = 0; m < 4; ++m)
#pragma unroll
    for (int n = 0; n < 4; ++n) acc[m][n] = (f32x4){0.f, 0.f, 0.f, 0.f};

  float4 s0[4], s1[4];   // two named in-flight B reg sets: B(j) in set[j&1]

#define ISSUE_A(buf, kt)                                                        \
  {                                                                             \
    _Pragma("unroll")                                                           \
    for (int i = 0; i < 4; ++i)                                                 \
      __builtin_amdgcn_global_load_lds((GLV*)(Asrc + (size_t)i * 64 * K + (kt) * 64), \
                                       (LDSV*)&As[buf][(i * 512 + tid) * 8], 16, 0, 0); \
  }
#define ISSUE_B(dst, kt)                                                        \
  {                                                                             \
    const float* g = Bsrc + (kt) * 64;                                          \
    dst[0] = *(const float4*)(g);                                               \
    dst[1] = *(const float4*)(g + 4);                                           \
    dst[2] = *(const float4*)(g + 8);                                           \
    dst[3] = *(const float4*)(g + 12);                                          \
  }
#define WRITE_B(buf, src)                                                       \
  {                                                                             \
    *(uint4*)&Bs[buf][bwo0] = cvt8u(src[0], src[1]);                            \
    *(uint4*)&Bs[buf][bwo1] = cvt8u(src[2], src[3]);                            \
  }

  // ---- prologue: issue tiles 0 and 1; retire tile 0; publish B(0)
  ISSUE_A(0, 0); ISSUE_B(s0, 0);
  ISSUE_A(1, 1); ISSUE_B(s1, 1);
  asm volatile("s_waitcnt vmcnt(8)" ::: "memory");   // tile 0 landed; tile 1 flies
  __builtin_amdgcn_sched_barrier(0);
  WRITE_B(0, s0);
  asm volatile("s_waitcnt lgkmcnt(0)" ::: "memory");
  __builtin_amdgcn_sched_barrier(0);
  __builtin_amdgcn_s_barrier();
  __builtin_amdgcn_sched_barrier(0);

  int bufc = 0, bufn1 = 1, bufn2 = 2;
  for (int t = 0; t < NK; ++t) {
    // issue tile t+2 (its buffer's readers finished before end-of-(t-1) barrier)
    if (t + 2 < NK) {
      ISSUE_A(bufn2, t + 2);
      if ((t & 1) == 0) { ISSUE_B(s0, t + 2); } else { ISSUE_B(s1, t + 2); }
      asm volatile("s_waitcnt vmcnt(8)" ::: "memory");  // ALL of (t+1) retired
      __builtin_amdgcn_sched_barrier(0);
    } else {
      asm volatile("s_waitcnt vmcnt(0)" ::: "memory");
      __builtin_amdgcn_sched_barrier(0);
    }
    // publish B(t+1) into bufn1 (read next iter; nobody reads bufn1 this iter)
    if (t + 1 < NK) {
      if ((t & 1) == 0) { WRITE_B(bufn1, s1); } else { WRITE_B(bufn1, s0); }
    }

    // ---- compute tile t from bufc (2 ksteps of 32)
    short8 a8[4], b8[4];
#pragma unroll
    for (int m = 0; m < 4; ++m) a8[m] = *(const short8*)&As[bufc][aro + m * 1024 + ch0];
#pragma unroll
    for (int n = 0; n < 4; ++n) b8[n] = *(const short8*)&Bs[bufc][bro + n * 1024 + ch0];
#pragma unroll
    for (int m = 0; m < 4; ++m)
#pragma unroll
      for (int n = 0; n < 4; ++n)
        acc[m][n] = __builtin_amdgcn_mfma_f32_16x16x32_bf16(a8[m], b8[n], acc[m][n], 0, 0, 0);
#pragma unroll
    for (int m = 0; m < 4; ++m) a8[m] = *(const short8*)&As[bufc][aro + m * 1024 + ch1];
#pragma unroll
    for (int n = 0; n < 4; ++n) b8[n] = *(const short8*)&Bs[bufc][bro + n * 1024 + ch1];
#pragma unroll
    for (int m = 0; m < 4; ++m)
#pragma unroll
      for (int n = 0; n < 4; ++n)
        acc[m][n] = __builtin_amdgcn_mfma_f32_16x16x32_bf16(a8[m], b8[n], acc[m][n], 0, 0, 0);

    // ds_writes (B(t+1)) + ds_reads retired, then barrier; t+2 vmem stays out
    asm volatile("s_waitcnt lgkmcnt(0)" ::: "memory");
    __builtin_amdgcn_sched_barrier(0);
    __builtin_amdgcn_s_barrier();
    __builtin_amdgcn_sched_barrier(0);

    const int b0 = bufc;
    bufc = bufn1; bufn1 = bufn2; bufn2 = b0;
  }
#undef ISSUE_A
#undef ISSUE_B
#undef WRITE_B

  // ---- epilogue
  float bv[4];
#pragma unroll
  for (int n = 0; n < 4; ++n)
    bv[n] = bias[(size_t)e * N + bn * 128 + wc * 64 + n * 16 + fr];

  if (EPI == 1) {
    // LDS-coalesced gelu->bf16 (R15-validated pattern, 256 rows, one pass).
    bf16* He = Hout + (size_t)e * MPE * N;
    bf16* Ls = &As[0][0];   // 64 KB = As[0..1]
    __syncthreads();
#pragma unroll
    for (int m = 0; m < 4; ++m) {
#pragma unroll
      for (int j = 0; j < 4; ++j) {
        const int lr = wr * 64 + m * 16 + fq * 4 + j;   // 0..255
#pragma unroll
        for (int n = 0; n < 4; ++n) {
          const int c = wc * 64 + n * 16 + fr;          // 0..127
          const int byteoff = lr * 256 + ((c * 2) ^ ((lr & 7) << 4));
          Ls[byteoff >> 1] = __float2bfloat16(fast_gelu(acc[m][n][j] + bv[n]));
        }
      }
    }
    __syncthreads();
#pragma unroll
    for (int q = 0; q < 8; ++q) {
      const int o = (tid + q * 512) * 16;        // byte offset in 64 KB
      const int lr = o >> 8;                     // 0..255
      const int cb = o & 255;                    // byte-in-row
      const int sb = lr * 256 + (cb ^ ((lr & 7) << 4));
      uint4 v = *(const uint4*)((const char*)Ls + sb);
      *(uint4*)&He[(size_t)(bm * 256 + lr) * N + bn * 128 + (cb >> 1)] = v;
    }
  } else {
#pragma unroll
    for (int m = 0; m < 4; ++m) {
#pragma unroll
      for (int j = 0; j < 4; ++j) {
        const int grow = e * MPE + bm * 256 + wr * 64 + m * 16 + fq * 4 + j;
        const int drow = perm[grow];
        float* orow = Oout + (size_t)drow * N;
#pragma unroll
        for (int n = 0; n < 4; ++n) {
          const int col = bn * 128 + wc * 64 + n * 16 + fr;
          orow[col] = acc[m][n][j] + bv[n];
        }
      }
    }
  }
}

// ---------------- residual + LayerNorm (in place on out) ----------------
__global__ __launch_bounds__(256)
void ln_resid_kernel(float* __restrict__ out, const float* __restrict__ hs,
                     const float* __restrict__ gamma, const float* __restrict__ beta) {
  const int r = blockIdx.x;
  const int t = threadIdx.x;
  float4 o = ((const float4*)(out + (size_t)r * H_DIM))[t];
  float4 h = ((const float4*)(hs  + (size_t)r * H_DIM))[t];
  float v0 = o.x + h.x, v1 = o.y + h.y, v2 = o.z + h.z, v3 = o.w + h.w;
  float s  = v0 + v1 + v2 + v3;
  float sq = v0 * v0 + v1 * v1 + v2 * v2 + v3 * v3;
#pragma unroll
  for (int off = 32; off > 0; off >>= 1) {
    s  += __shfl_down(s, off);
    sq += __shfl_down(sq, off);
  }
  __shared__ float ss[4], ssq[4];
  const int wv = t >> 6;
  if ((t & 63) == 0) { ss[wv] = s; ssq[wv] = sq; }
  __syncthreads();
  s  = ss[0] + ss[1] + ss[2] + ss[3];
  sq = ssq[0] + ssq[1] + ssq[2] + ssq[3];
  const float mu  = s * (1.0f / (float)H_DIM);
  const float var = sq * (1.0f / (float)H_DIM) - mu * mu;
  const float rs  = rsqrtf(var + 1e-12f);
  float4 g = ((const float4*)gamma)[t];
  float4 b = ((const float4*)beta)[t];
  float4 rr;
  rr.x = (v0 - mu) * rs * g.x + b.x;
  rr.y = (v1 - mu) * rs * g.y + b.y;
  rr.z = (v2 - mu) * rs * g.z + b.z;
  rr.w = (v3 - mu) * rs * g.w + b.w;
  ((float4*)(out + (size_t)r * H_DIM))[t] = rr;
}

extern "C" void kernel_launch(void* const* d_in, const int* in_sizes, int n_in,
                              void* d_out, int out_size, void* d_ws, size_t ws_size,
                              hipStream_t stream) {
  const float* hs    = (const float*)d_in[0];
  const int*   perm  = (const int*)d_in[1];
  const float* w1    = (const float*)d_in[2];
  const float* b1    = (const float*)d_in[3];
  const float* w2    = (const float*)d_in[4];
  const float* b2    = (const float*)d_in[5];
  const float* gamma = (const float*)d_in[6];
  const float* beta  = (const float*)d_in[7];
  float* out = (float*)d_out;

  bf16* xp   = (bf16*)d_ws;                                                  // 16 MB
  bf16* hbuf = (bf16*)((char*)d_ws + (size_t)T_NUM * H_DIM * sizeof(bf16));  // 64 MB

  gather_cast_kernel<<<T_NUM, 256, 0, stream>>>(hs, perm, (uint32_t*)xp);

  // GEMM1: 2 bm x 32 bn x 16 e = 1024 blocks, K=1024 (16 iters)
  moe_gemm_kernel<1, I_DIM, H_DIM, 5, 1024><<<1024, 512, 0, stream>>>(
      xp, w1, b1, hbuf, nullptr, nullptr);

  // GEMM2: 2 bm x 8 bn x 16 e = 256 blocks, K=4096 (64 iters)
  moe_gemm_kernel<0, H_DIM, I_DIM, 3, 256><<<256, 512, 0, stream>>>(
      hbuf, w2, b2, nullptr, out, perm);

  ln_resid_kernel<<<T_NUM, 256, 0, stream>>>(out, hs, gamma, beta);
}

// Round 18
// 320.642 us; speedup vs baseline: 1.1464x; 1.1464x over previous
//
#include <hip/hip_runtime.h>
#include <hip/hip_bf16.h>
#include <stdint.h>

#define E_NUM 16
#define T_NUM 8192
#define H_DIM 1024
#define I_DIM 4096
#define MPE   512   // tokens per expert

typedef __attribute__((ext_vector_type(8))) short short8;
typedef __attribute__((ext_vector_type(4))) float f32x4;
using bf16 = __hip_bfloat16;

typedef const __attribute__((address_space(1))) void GLV;
typedef __attribute__((address_space(3))) void LDSV;

__device__ __forceinline__ uint32_t pack2_bf16(float a, float b) {
  union { float f; uint32_t u; } ua, ub;
  ua.f = a; ub.f = b;
  uint32_t x = ua.u + (0x7FFFu + ((ua.u >> 16) & 1u));
  uint32_t y = ub.u + (0x7FFFu + ((ub.u >> 16) & 1u));
  return (x >> 16) | (y & 0xFFFF0000u);
}

// float4 -> uint2 of 4 bf16 (RNE, v_cvt_pk_bf16_f32)
__device__ __forceinline__ uint2 cvt4u(float4 a) {
  union { uint2 u; __hip_bfloat162 h[2]; } r;
  r.h[0] = __float22bfloat162_rn({a.x, a.y});
  r.h[1] = __float22bfloat162_rn({a.z, a.w});
  return r.u;
}

// fast GELU (validated R10/R12/R13/R15: absmax unchanged at 0.03125)
__device__ __forceinline__ float fast_gelu(float x) {
  const float p = x * fmaf(x * x, -0.0713548162726f, -1.59576912161f);
  return x * __builtin_amdgcn_rcpf(1.0f + __expf(p));
}

// ---------------- gather + cast: xp[r] = bf16(hs[perm[r]]) ----------------
__global__ __launch_bounds__(256)
void gather_cast_kernel(const float* __restrict__ hs, const int* __restrict__ perm,
                        uint32_t* __restrict__ xp) {
  const int r = blockIdx.x;
  const int t = threadIdx.x;
  const int src = perm[r];
  float4 v = ((const float4*)(hs + (size_t)src * H_DIM))[t];
  uint2 o;
  o.x = pack2_bf16(v.x, v.y);
  o.y = pack2_bf16(v.z, v.w);
  ((uint2*)(xp + (size_t)r * (H_DIM / 2)))[t] = o;
}

// ------- grouped GEMM: BM=512/BN=128/BK=32, 16 waves, bf16-B in LDS --------
// C = A(bf16,[E][512][KFULL]) * B(f32,[E][N][KFULL])^T over K window.
// R16's triple-buffered counted pipeline (vmcnt(3), raw s_barrier) with B
// reg-staged 2 tiles ahead: f32->regs -> 4 cvt_pk -> 8B swizzled ds_write into
// pair-packed [64][64] bf16 tiles (A's validated chunk^(row&7) geometry).
// Per-iter LDS reads 192->128 KB; cvt 16->4 per thread (write-side, once).
// EPI=1: gelu -> bf16 Hout via LDS-coalesced epilogue (R15-validated).
// EPI=0: f32 partial to Pout (split-K).
template<int EPI, int KSPLIT, int N, int KFULL, int KLEN, int LOG_NBN>
__global__ __launch_bounds__(1024, 4)
void moe_gemm_kernel(const bf16* __restrict__ A, const float* __restrict__ Bw,
                     const float* __restrict__ bias, bf16* __restrict__ Hout,
                     float* __restrict__ Pout) {
  constexpr int NK = KLEN / 32;
  __shared__ bf16 As[3][512 * 32];   // 32 KB each (epilogue reuses As[0..1])
  __shared__ bf16 Bs[3][64 * 64];    // 8 KB each: [64 lds-rows][64] pair-packed
                                     // lds-row p holds cols p and p+64

  // bijective chunked XCD swizzle (m204); nwg % 8 == 0
  const int nwg = gridDim.x, qx = nwg >> 3, orig = blockIdx.x;
  const int wg = (orig & 7) * qx + (orig >> 3);
  const int bn   = wg & ((1 << LOG_NBN) - 1);
  const int rest = wg >> LOG_NBN;
  const int ks = (KSPLIT == 2) ? (rest & 1) : 0;
  const int e  = (KSPLIT == 2) ? (rest >> 1) : rest;
  const int K0 = ks * KLEN;

  const int tid = threadIdx.x;
  const int l = tid & 63;
  const int w = tid >> 6;                  // 0..15
  const int wr = w >> 1, wc = w & 1;       // 8 M-waves x 2 N-waves
  const int fr = l & 15, fq = l >> 4;
  const int rx = fr & 7;

  const bf16*  Ae = A  + (size_t)e * MPE * KFULL + K0;
  const float* Be = Bw + ((size_t)e * N + (size_t)bn * 128) * KFULL + K0;

  // A staging (R8/R15/R16-validated): lds-row p = i*128 + (tid>>3), slot s =
  // tid&7, g = s^(p&7); real row = p + 256*(g>>2), k-chunk (g&3)*8.
  const int apq = tid >> 3;
  const int ag  = (tid & 7) ^ (apq & 7);
  const bf16* As0 = Ae + (size_t)(apq       + 256 * (ag >> 2)) * KFULL + (ag & 3) * 8;
  const bf16* As1 = Ae + (size_t)(apq + 128 + 256 * (ag >> 2)) * KFULL + (ag & 3) * 8;

  // B staging: col c = tid>>3 (0..127), seg s = tid&7 (4 f32).  Write as bf16
  // into packed row p = c&63, half h = c>>6: 16B-chunk lc = h*4 + (s>>1),
  // phys pc = lc ^ (p&7), +(s&1)*4 elems.  (A's validated swizzle family.)
  const int bc = tid >> 3, bsg = tid & 7;
  const float* Bsrc = Be + (size_t)bc * KFULL + bsg * 4;
  const int bp  = bc & 63;
  const int bwo = bp * 64 + (((((bc >> 6) << 2) | (bsg >> 1)) ^ (bp & 7)) << 3)
                + (bsg & 1) * 4;

  // fragment read offsets
  // A (R16-validated): p' = (wr&3)*64 + m*16 + fr, slot ((wr>>2)<<2|fq)^rx
  const int aso = (((((wr >> 2) << 2)) | fq) ^ rx) * 8;
  // B: col c = wc*64 + n*16 + fr -> p = n*16+fr (wc*64 -> half h = wc),
  //    chunk (wc*4 + fq) ^ rx   [ (n*16+fr)&7 == rx ]
  const int bro = fr * 64 + ((((wc << 2) | fq) ^ rx) << 3);   // + n*1024

  f32x4 acc[4][4];
#pragma unroll
  for (int m = 0; m < 4; ++m)
#pragma unroll
    for (int n = 0; n < 4; ++n) acc[m][n] = (f32x4){0.f, 0.f, 0.f, 0.f};

  float4 s0, s1;   // two named in-flight B reg sets: B(j) in set j&1

#define ISSUE_A(buf, kt)                                                            \
  {                                                                                 \
    __builtin_amdgcn_global_load_lds((GLV*)(As0 + (kt) * 32),                       \
                                     (LDSV*)&As[buf][tid * 8], 16, 0, 0);           \
    __builtin_amdgcn_global_load_lds((GLV*)(As1 + (kt) * 32),                       \
                                     (LDSV*)&As[buf][(1024 + tid) * 8], 16, 0, 0);  \
  }
#define ISSUE_B(dst, kt)  { dst = *(const float4*)(Bsrc + (kt) * 32); }
#define WRITE_B(buf, src) { *(uint2*)&Bs[buf][bwo] = cvt4u(src); }

  // ---- prologue: issue tiles 0,1 (3 VMEM ops each); retire tile 0; publish B(0)
  ISSUE_A(0, 0); ISSUE_B(s0, 0);
  ISSUE_A(1, 1); ISSUE_B(s1, 1);
  asm volatile("s_waitcnt vmcnt(3)" ::: "memory");   // tile 0 landed; tile 1 flies
  __builtin_amdgcn_sched_barrier(0);
  WRITE_B(0, s0);
  asm volatile("s_waitcnt lgkmcnt(0)" ::: "memory");
  __builtin_amdgcn_sched_barrier(0);
  __builtin_amdgcn_s_barrier();
  __builtin_amdgcn_sched_barrier(0);

  int bufc = 0, bufn1 = 1, bufn2 = 2;
  for (int t = 0; t < NK; ++t) {
    // issue tile t+2; retire ALL of tile t+1 (A glds + B regs); publish B(t+1)
    if (t + 2 < NK) {
      ISSUE_A(bufn2, t + 2);
      if ((t & 1) == 0) { ISSUE_B(s0, t + 2); } else { ISSUE_B(s1, t + 2); }
      asm volatile("s_waitcnt vmcnt(3)" ::: "memory");
      __builtin_amdgcn_sched_barrier(0);
    } else {
      asm volatile("s_waitcnt vmcnt(0)" ::: "memory");
      __builtin_amdgcn_sched_barrier(0);
    }
    if (t + 1 < NK) {
      if ((t & 1) == 0) { WRITE_B(bufn1, s1); } else { WRITE_B(bufn1, s0); }
    }

    // ---- compute tile t (one kstep of 32)
    short8 a8[4];
#pragma unroll
    for (int m = 0; m < 4; ++m)
      a8[m] = *(const short8*)&As[bufc][((wr & 3) * 64 + m * 16 + fr) * 64 + aso];
    short8 b8[4];
#pragma unroll
    for (int n = 0; n < 4; ++n)
      b8[n] = *(const short8*)&Bs[bufc][bro + n * 1024];
#pragma unroll
    for (int m = 0; m < 4; ++m)
#pragma unroll
      for (int n = 0; n < 4; ++n)
        acc[m][n] = __builtin_amdgcn_mfma_f32_16x16x32_bf16(a8[m], b8[n], acc[m][n], 0, 0, 0);

    // ds_write B(t+1) + ds_reads retired; barrier; t+2 vmem stays in flight
    asm volatile("s_waitcnt lgkmcnt(0)" ::: "memory");
    __builtin_amdgcn_sched_barrier(0);
    __builtin_amdgcn_s_barrier();
    __builtin_amdgcn_sched_barrier(0);

    const int b0 = bufc;
    bufc = bufn1; bufn1 = bufn2; bufn2 = b0;
  }
#undef ISSUE_A
#undef ISSUE_B
#undef WRITE_B
  __syncthreads();   // all waves done before epilogue LDS reuse

  // ---- epilogue
  if (EPI == 1) {
    float bv[4];
#pragma unroll
    for (int n = 0; n < 4; ++n)
      bv[n] = bias[(size_t)e * N + bn * 128 + wc * 64 + n * 16 + fr];
    bf16* He = Hout + (size_t)e * MPE * N;

    // LDS-coalesced (R15-validated): 2 passes of 256 rows through As[0..1].
    bf16* Ls = &As[0][0];
#pragma unroll
    for (int P = 0; P < 2; ++P) {
      if ((wr >> 2) == P) {
        const int wrl = wr & 3;
#pragma unroll
        for (int m = 0; m < 4; ++m) {
#pragma unroll
          for (int j = 0; j < 4; ++j) {
            const int lr = wrl * 64 + m * 16 + fq * 4 + j;   // 0..255
#pragma unroll
            for (int n = 0; n < 4; ++n) {
              const int c = wc * 64 + n * 16 + fr;
              const int byteoff = lr * 256 + ((c * 2) ^ ((lr & 7) << 4));
              Ls[byteoff >> 1] = __float2bfloat16(fast_gelu(acc[m][n][j] + bv[n]));
            }
          }
        }
      }
      __syncthreads();
#pragma unroll
      for (int q = 0; q < 4; ++q) {
        const int o = (tid + q * 1024) * 16;       // byte offset in 64 KB
        const int lr = o >> 8;                     // 0..255
        const int cb = o & 255;                    // byte-in-row
        const int sb = lr * 256 + (cb ^ ((lr & 7) << 4));
        uint4 v = *(const uint4*)((const char*)Ls + sb);
        *(uint4*)&He[(size_t)(P * 256 + lr) * N + bn * 128 + (cb >> 1)] = v;
      }
      __syncthreads();
    }
  } else {
    float* Pd = Pout + (size_t)ks * T_NUM * H_DIM + (size_t)e * MPE * N;
#pragma unroll
    for (int m = 0; m < 4; ++m) {
#pragma unroll
      for (int j = 0; j < 4; ++j) {
        const int row = wr * 64 + m * 16 + fq * 4 + j;
#pragma unroll
        for (int n = 0; n < 4; ++n) {
          const int col = bn * 128 + wc * 64 + n * 16 + fr;
          Pd[(size_t)row * N + col] = acc[m][n][j];
        }
      }
    }
  }
}

// -------- reduce partials + bias + residual + LayerNorm + scatter ----------
__global__ __launch_bounds__(256)
void ln_resid2_kernel(float* __restrict__ out, const float* __restrict__ hs,
                      const float* __restrict__ p0, const float* __restrict__ p1,
                      const float* __restrict__ b2, const float* __restrict__ gamma,
                      const float* __restrict__ beta, const int* __restrict__ perm,
                      const int two) {
  const int r = blockIdx.x;
  const int t = threadIdx.x;
  const int e = r >> 9;
  const int drow = perm[r];
  float4 a = ((const float4*)(p0 + (size_t)r * H_DIM))[t];
  if (two) {
    float4 b = ((const float4*)(p1 + (size_t)r * H_DIM))[t];
    a.x += b.x; a.y += b.y; a.z += b.z; a.w += b.w;
  }
  float4 bb = ((const float4*)(b2 + (size_t)e * H_DIM))[t];
  float4 h  = ((const float4*)(hs + (size_t)drow * H_DIM))[t];
  float v0 = a.x + bb.x + h.x, v1 = a.y + bb.y + h.y;
  float v2 = a.z + bb.z + h.z, v3 = a.w + bb.w + h.w;
  float s  = v0 + v1 + v2 + v3;
  float sq = v0 * v0 + v1 * v1 + v2 * v2 + v3 * v3;
#pragma unroll
  for (int off = 32; off > 0; off >>= 1) {
    s  += __shfl_down(s, off);
    sq += __shfl_down(sq, off);
  }
  __shared__ float ss[4], ssq[4];
  const int wv = t >> 6;
  if ((t & 63) == 0) { ss[wv] = s; ssq[wv] = sq; }
  __syncthreads();
  s  = ss[0] + ss[1] + ss[2] + ss[3];
  sq = ssq[0] + ssq[1] + ssq[2] + ssq[3];
  const float mu  = s * (1.0f / (float)H_DIM);
  const float var = sq * (1.0f / (float)H_DIM) - mu * mu;
  const float rs  = rsqrtf(var + 1e-12f);
  float4 g = ((const float4*)gamma)[t];
  float4 b = ((const float4*)beta)[t];
  float4 rr;
  rr.x = (v0 - mu) * rs * g.x + b.x;
  rr.y = (v1 - mu) * rs * g.y + b.y;
  rr.z = (v2 - mu) * rs * g.z + b.z;
  rr.w = (v3 - mu) * rs * g.w + b.w;
  ((float4*)(out + (size_t)drow * H_DIM))[t] = rr;
}

extern "C" void kernel_launch(void* const* d_in, const int* in_sizes, int n_in,
                              void* d_out, int out_size, void* d_ws, size_t ws_size,
                              hipStream_t stream) {
  const float* hs    = (const float*)d_in[0];
  const int*   perm  = (const int*)d_in[1];
  const float* w1    = (const float*)d_in[2];
  const float* b1    = (const float*)d_in[3];
  const float* w2    = (const float*)d_in[4];
  const float* b2    = (const float*)d_in[5];
  const float* gamma = (const float*)d_in[6];
  const float* beta  = (const float*)d_in[7];
  float* out = (float*)d_out;

  const size_t xp_b   = (size_t)T_NUM * H_DIM * sizeof(bf16);   // 16 MB
  const size_t hbuf_b = (size_t)T_NUM * I_DIM * sizeof(bf16);   // 64 MB
  const size_t part_b = (size_t)T_NUM * H_DIM * sizeof(float);  // 32 MB each

  bf16*  xp   = (bf16*)d_ws;
  bf16*  hbuf = (bf16*)((char*)d_ws + xp_b);
  float* pbuf = (float*)((char*)d_ws + xp_b + hbuf_b);

  gather_cast_kernel<<<T_NUM, 256, 0, stream>>>(hs, perm, (uint32_t*)xp);

  // GEMM1: BM=512 (w1 fetched once). grid = 32 bn x 16 e = 512
  moe_gemm_kernel<1, 1, I_DIM, H_DIM, H_DIM, 5>
      <<<512, 1024, 0, stream>>>(xp, w1, b1, hbuf, nullptr);

  if (ws_size >= xp_b + hbuf_b + 2 * part_b) {
    // GEMM2 split-K=2: grid = 8 bn x 2 ks x 16 e = 256
    moe_gemm_kernel<0, 2, H_DIM, I_DIM, I_DIM / 2, 3>
        <<<256, 1024, 0, stream>>>(hbuf, w2, nullptr, nullptr, pbuf);
    ln_resid2_kernel<<<T_NUM, 256, 0, stream>>>(out, hs, pbuf, pbuf + (size_t)T_NUM * H_DIM,
                                                b2, gamma, beta, perm, 1);
  } else {
    moe_gemm_kernel<0, 1, H_DIM, I_DIM, I_DIM, 3>
        <<<128, 1024, 0, stream>>>(hbuf, w2, nullptr, nullptr, pbuf);
    ln_resid2_kernel<<<T_NUM, 256, 0, stream>>>(out, hs, pbuf, nullptr,
                                                b2, gamma, beta, perm, 0);
  }
}

// Round 19
// 293.819 us; speedup vs baseline: 1.2511x; 1.0913x over previous
//
#include <hip/hip_runtime.h>
#include <hip/hip_bf16.h>
#include <stdint.h>

#define E_NUM 16
#define T_NUM 8192
#define H_DIM 1024
#define I_DIM 4096
#define MPE   512   // tokens per expert

typedef __attribute__((ext_vector_type(8))) short short8;
typedef __attribute__((ext_vector_type(4))) float f32x4;
using bf16 = __hip_bfloat16;

typedef const __attribute__((address_space(1))) void GLV;
typedef __attribute__((address_space(3))) void LDSV;

__device__ __forceinline__ uint32_t pack2_bf16(float a, float b) {
  union { float f; uint32_t u; } ua, ub;
  ua.f = a; ub.f = b;
  uint32_t x = ua.u + (0x7FFFu + ((ua.u >> 16) & 1u));
  uint32_t y = ub.u + (0x7FFFu + ((ub.u >> 16) & 1u));
  return (x >> 16) | (y & 0xFFFF0000u);
}

// float4 -> uint2 of 4 bf16 (RNE, v_cvt_pk_bf16_f32)
__device__ __forceinline__ uint2 cvt4u(float4 a) {
  union { uint2 u; __hip_bfloat162 h[2]; } r;
  r.h[0] = __float22bfloat162_rn({a.x, a.y});
  r.h[1] = __float22bfloat162_rn({a.z, a.w});
  return r.u;
}

// fast GELU (validated R10/R12/R13/R15: absmax unchanged at 0.03125)
__device__ __forceinline__ float fast_gelu(float x) {
  const float p = x * fmaf(x * x, -0.0713548162726f, -1.59576912161f);
  return x * __builtin_amdgcn_rcpf(1.0f + __expf(p));
}

// ---------------- gather + cast: xp[r] = bf16(hs[perm[r]]) ----------------
__global__ __launch_bounds__(256)
void gather_cast_kernel(const float* __restrict__ hs, const int* __restrict__ perm,
                        uint32_t* __restrict__ xp) {
  const int r = blockIdx.x;
  const int t = threadIdx.x;
  const int src = perm[r];
  float4 v = ((const float4*)(hs + (size_t)src * H_DIM))[t];
  uint2 o;
  o.x = pack2_bf16(v.x, v.y);
  o.y = pack2_bf16(v.z, v.w);
  ((uint2*)(xp + (size_t)r * (H_DIM / 2)))[t] = o;
}

// --- grouped GEMM: BM=512/BN=128/BK=32, bf16-B, DBUF 80 KB -> 2 blocks/CU ---
// C = A(bf16,[E][512][KFULL]) * B(f32,[E][N][KFULL])^T over K window.
// R18's kernel with double buffering (2 x 40 KB = 80 KB LDS): two blocks
// co-resident per CU (32 waves) so cross-block overlap (m114) hides the
// end-of-iter drain.  B: f32->reg at top of iter t -> vmcnt(2) after compute
// -> cvt_pk -> swizzled ds_write into pair-packed [64][64] bf16 (R18-validated
// geometry).  A: glds-direct (R8/R15/R16-validated).
// EPI=1: gelu -> bf16 Hout via LDS-coalesced epilogue.  EPI=0: f32 partials.
template<int EPI, int KSPLIT, int N, int KFULL, int KLEN, int LOG_NBN>
__global__ __launch_bounds__(1024, 4)
void moe_gemm_kernel(const bf16* __restrict__ A, const float* __restrict__ Bw,
                     const float* __restrict__ bias, bf16* __restrict__ Hout,
                     float* __restrict__ Pout) {
  constexpr int NK = KLEN / 32;
  __shared__ bf16 As[2][512 * 32];   // 32 KB each (epilogue reuses As[0..1])
  __shared__ bf16 Bs[2][64 * 64];    // 8 KB each: [64 lds-rows][64] pair-packed

  // bijective chunked XCD swizzle (m204); nwg % 8 == 0
  const int nwg = gridDim.x, qx = nwg >> 3, orig = blockIdx.x;
  const int wg = (orig & 7) * qx + (orig >> 3);
  const int bn   = wg & ((1 << LOG_NBN) - 1);
  const int rest = wg >> LOG_NBN;
  const int ks = (KSPLIT == 2) ? (rest & 1) : 0;
  const int e  = (KSPLIT == 2) ? (rest >> 1) : rest;
  const int K0 = ks * KLEN;

  const int tid = threadIdx.x;
  const int l = tid & 63;
  const int w = tid >> 6;                  // 0..15
  const int wr = w >> 1, wc = w & 1;       // 8 M-waves x 2 N-waves
  const int fr = l & 15, fq = l >> 4;
  const int rx = fr & 7;

  const bf16*  Ae = A  + (size_t)e * MPE * KFULL + K0;
  const float* Be = Bw + ((size_t)e * N + (size_t)bn * 128) * KFULL + K0;

  // A staging (validated): lds-row p = i*128 + (tid>>3), slot s = tid&7,
  // g = s^(p&7); real row = p + 256*(g>>2), k-chunk (g&3)*8.
  const int apq = tid >> 3;
  const int ag  = (tid & 7) ^ (apq & 7);
  const bf16* As0 = Ae + (size_t)(apq       + 256 * (ag >> 2)) * KFULL + (ag & 3) * 8;
  const bf16* As1 = Ae + (size_t)(apq + 128 + 256 * (ag >> 2)) * KFULL + (ag & 3) * 8;

  // B staging (R18-validated): col c = tid>>3, seg s = tid&7 (4 f32); packed
  // row p = c&63, half h = c>>6; chunk lc = h*4 + (s>>1), phys lc^(p&7).
  const int bc = tid >> 3, bsg = tid & 7;
  const float* Bsrc = Be + (size_t)bc * KFULL + bsg * 4;
  const int bp  = bc & 63;
  const int bwo = bp * 64 + (((((bc >> 6) << 2) | (bsg >> 1)) ^ (bp & 7)) << 3)
                + (bsg & 1) * 4;

  // fragment read offsets (R18-validated)
  const int aso = (((((wr >> 2) << 2)) | fq) ^ rx) * 8;
  const int bro = fr * 64 + ((((wc << 2) | fq) ^ rx) << 3);   // + n*1024

  f32x4 acc[4][4];
#pragma unroll
  for (int m = 0; m < 4; ++m)
#pragma unroll
    for (int n = 0; n < 4; ++n) acc[m][n] = (f32x4){0.f, 0.f, 0.f, 0.f};

  float4 breg;

  // issue order matters: B first, then A -> vmcnt(2) == B landed
#define ISSUE(buf, kt)                                                              \
  {                                                                                 \
    breg = *(const float4*)(Bsrc + (kt) * 32);                                      \
    __builtin_amdgcn_global_load_lds((GLV*)(As0 + (kt) * 32),                       \
                                     (LDSV*)&As[buf][tid * 8], 16, 0, 0);           \
    __builtin_amdgcn_global_load_lds((GLV*)(As1 + (kt) * 32),                       \
                                     (LDSV*)&As[buf][(1024 + tid) * 8], 16, 0, 0);  \
  }
#define WRITE_B(buf) { *(uint2*)&Bs[buf][bwo] = cvt4u(breg); }

  // ---- prologue: stage tile 0 fully
  ISSUE(0, 0);
  asm volatile("s_waitcnt vmcnt(2)" ::: "memory");
  __builtin_amdgcn_sched_barrier(0);
  WRITE_B(0);
  asm volatile("s_waitcnt vmcnt(0) lgkmcnt(0)" ::: "memory");
  __builtin_amdgcn_sched_barrier(0);
  __builtin_amdgcn_s_barrier();
  __builtin_amdgcn_sched_barrier(0);

  for (int t = 0; t < NK; ++t) {
    const int cur = t & 1, nxt = cur ^ 1;
    const bool more = (t + 1) < NK;

    if (more) ISSUE(nxt, t + 1);   // 3 VMEM ops fly across the compute

    // ---- compute tile t (one kstep of 32)
    short8 a8[4];
#pragma unroll
    for (int m = 0; m < 4; ++m)
      a8[m] = *(const short8*)&As[cur][((wr & 3) * 64 + m * 16 + fr) * 64 + aso];
    short8 b8[4];
#pragma unroll
    for (int n = 0; n < 4; ++n)
      b8[n] = *(const short8*)&Bs[cur][bro + n * 1024];
#pragma unroll
    for (int m = 0; m < 4; ++m)
#pragma unroll
      for (int n = 0; n < 4; ++n)
        acc[m][n] = __builtin_amdgcn_mfma_f32_16x16x32_bf16(a8[m], b8[n], acc[m][n], 0, 0, 0);

    if (more) {
      // B(t+1) float4 landed (2 A-glds may still be out); publish it
      asm volatile("s_waitcnt vmcnt(2)" ::: "memory");
      __builtin_amdgcn_sched_barrier(0);
      WRITE_B(nxt);
      // A(t+1) glds + B ds_write + frag ds_reads drained; barrier.
      // Cross-block overlap (2 blocks/CU) hides this drain.
      asm volatile("s_waitcnt vmcnt(0) lgkmcnt(0)" ::: "memory");
      __builtin_amdgcn_sched_barrier(0);
      __builtin_amdgcn_s_barrier();
      __builtin_amdgcn_sched_barrier(0);
    }
  }
#undef ISSUE
#undef WRITE_B
  __syncthreads();   // all waves done before epilogue LDS reuse

  // ---- epilogue
  if (EPI == 1) {
    float bv[4];
#pragma unroll
    for (int n = 0; n < 4; ++n)
      bv[n] = bias[(size_t)e * N + bn * 128 + wc * 64 + n * 16 + fr];
    bf16* He = Hout + (size_t)e * MPE * N;

    // LDS-coalesced (R15-validated): 2 passes of 256 rows through As[0..1].
    bf16* Ls = &As[0][0];
#pragma unroll
    for (int P = 0; P < 2; ++P) {
      if ((wr >> 2) == P) {
        const int wrl = wr & 3;
#pragma unroll
        for (int m = 0; m < 4; ++m) {
#pragma unroll
          for (int j = 0; j < 4; ++j) {
            const int lr = wrl * 64 + m * 16 + fq * 4 + j;   // 0..255
#pragma unroll
            for (int n = 0; n < 4; ++n) {
              const int c = wc * 64 + n * 16 + fr;
              const int byteoff = lr * 256 + ((c * 2) ^ ((lr & 7) << 4));
              Ls[byteoff >> 1] = __float2bfloat16(fast_gelu(acc[m][n][j] + bv[n]));
            }
          }
        }
      }
      __syncthreads();
#pragma unroll
      for (int q = 0; q < 4; ++q) {
        const int o = (tid + q * 1024) * 16;       // byte offset in 64 KB
        const int lr = o >> 8;                     // 0..255
        const int cb = o & 255;                    // byte-in-row
        const int sb = lr * 256 + (cb ^ ((lr & 7) << 4));
        uint4 v = *(const uint4*)((const char*)Ls + sb);
        *(uint4*)&He[(size_t)(P * 256 + lr) * N + bn * 128 + (cb >> 1)] = v;
      }
      __syncthreads();
    }
  } else {
    float* Pd = Pout + (size_t)ks * T_NUM * H_DIM + (size_t)e * MPE * N;
#pragma unroll
    for (int m = 0; m < 4; ++m) {
#pragma unroll
      for (int j = 0; j < 4; ++j) {
        const int row = wr * 64 + m * 16 + fq * 4 + j;
#pragma unroll
        for (int n = 0; n < 4; ++n) {
          const int col = bn * 128 + wc * 64 + n * 16 + fr;
          Pd[(size_t)row * N + col] = acc[m][n][j];
        }
      }
    }
  }
}

// -------- reduce partials + bias + residual + LayerNorm + scatter ----------
__global__ __launch_bounds__(256)
void ln_resid2_kernel(float* __restrict__ out, const float* __restrict__ hs,
                      const float* __restrict__ p0, const float* __restrict__ p1,
                      const float* __restrict__ b2, const float* __restrict__ gamma,
                      const float* __restrict__ beta, const int* __restrict__ perm,
                      const int two) {
  const int r = blockIdx.x;
  const int t = threadIdx.x;
  const int e = r >> 9;
  const int drow = perm[r];
  float4 a = ((const float4*)(p0 + (size_t)r * H_DIM))[t];
  if (two) {
    float4 b = ((const float4*)(p1 + (size_t)r * H_DIM))[t];
    a.x += b.x; a.y += b.y; a.z += b.z; a.w += b.w;
  }
  float4 bb = ((const float4*)(b2 + (size_t)e * H_DIM))[t];
  float4 h  = ((const float4*)(hs + (size_t)drow * H_DIM))[t];
  float v0 = a.x + bb.x + h.x, v1 = a.y + bb.y + h.y;
  float v2 = a.z + bb.z + h.z, v3 = a.w + bb.w + h.w;
  float s  = v0 + v1 + v2 + v3;
  float sq = v0 * v0 + v1 * v1 + v2 * v2 + v3 * v3;
#pragma unroll
  for (int off = 32; off > 0; off >>= 1) {
    s  += __shfl_down(s, off);
    sq += __shfl_down(sq, off);
  }
  __shared__ float ss[4], ssq[4];
  const int wv = t >> 6;
  if ((t & 63) == 0) { ss[wv] = s; ssq[wv] = sq; }
  __syncthreads();
  s  = ss[0] + ss[1] + ss[2] + ss[3];
  sq = ssq[0] + ssq[1] + ssq[2] + ssq[3];
  const float mu  = s * (1.0f / (float)H_DIM);
  const float var = sq * (1.0f / (float)H_DIM) - mu * mu;
  const float rs  = rsqrtf(var + 1e-12f);
  float4 g = ((const float4*)gamma)[t];
  float4 b = ((const float4*)beta)[t];
  float4 rr;
  rr.x = (v0 - mu) * rs * g.x + b.x;
  rr.y = (v1 - mu) * rs * g.y + b.y;
  rr.z = (v2 - mu) * rs * g.z + b.z;
  rr.w = (v3 - mu) * rs * g.w + b.w;
  ((float4*)(out + (size_t)drow * H_DIM))[t] = rr;
}

extern "C" void kernel_launch(void* const* d_in, const int* in_sizes, int n_in,
                              void* d_out, int out_size, void* d_ws, size_t ws_size,
                              hipStream_t stream) {
  const float* hs    = (const float*)d_in[0];
  const int*   perm  = (const int*)d_in[1];
  const float* w1    = (const float*)d_in[2];
  const float* b1    = (const float*)d_in[3];
  const float* w2    = (const float*)d_in[4];
  const float* b2    = (const float*)d_in[5];
  const float* gamma = (const float*)d_in[6];
  const float* beta  = (const float*)d_in[7];
  float* out = (float*)d_out;

  const size_t xp_b   = (size_t)T_NUM * H_DIM * sizeof(bf16);   // 16 MB
  const size_t hbuf_b = (size_t)T_NUM * I_DIM * sizeof(bf16);   // 64 MB
  const size_t part_b = (size_t)T_NUM * H_DIM * sizeof(float);  // 32 MB each

  bf16*  xp   = (bf16*)d_ws;
  bf16*  hbuf = (bf16*)((char*)d_ws + xp_b);
  float* pbuf = (float*)((char*)d_ws + xp_b + hbuf_b);

  gather_cast_kernel<<<T_NUM, 256, 0, stream>>>(hs, perm, (uint32_t*)xp);

  // GEMM1: BM=512 (w1 fetched once). grid = 32 bn x 16 e = 512 -> 2 blocks/CU
  moe_gemm_kernel<1, 1, I_DIM, H_DIM, H_DIM, 5>
      <<<512, 1024, 0, stream>>>(xp, w1, b1, hbuf, nullptr);

  if (ws_size >= xp_b + hbuf_b + 2 * part_b) {
    // GEMM2 split-K=2: grid = 8 bn x 2 ks x 16 e = 256... x2 rounds? No:
    // 8 bn x 2 ks x 16 e = 256 blocks; bump to 2/CU via KSPLIT=2 on 512 CUs
    // -> use 512 blocks: KSPLIT=2 gives 256; keep 256 (1/CU) is wasteful, so
    // run split-K=2 with BN=128 -> 256 blocks; dbuf still helps via pipeline.
    moe_gemm_kernel<0, 2, H_DIM, I_DIM, I_DIM / 2, 3>
        <<<256, 1024, 0, stream>>>(hbuf, w2, nullptr, nullptr, pbuf);
    ln_resid2_kernel<<<T_NUM, 256, 0, stream>>>(out, hs, pbuf, pbuf + (size_t)T_NUM * H_DIM,
                                                b2, gamma, beta, perm, 1);
  } else {
    moe_gemm_kernel<0, 1, H_DIM, I_DIM, I_DIM, 3>
        <<<128, 1024, 0, stream>>>(hbuf, w2, nullptr, nullptr, pbuf);
    ln_resid2_kernel<<<T_NUM, 256, 0, stream>>>(out, hs, pbuf, nullptr,
                                                b2, gamma, beta, perm, 0);
  }
}